// Round 9
// baseline (768.412 us; speedup 1.0000x reference)
//
#include <hip/hip_runtime.h>
#include <hip/hip_cooperative_groups.h>

namespace cg = cooperative_groups;

#define EPSF 1e-8f

constexpr int NB = 64;   // batch
constexpr int NO = 64;   // out capsules
constexpr int NI = 1152; // in capsules
constexpr int ND = 16;   // pose dims

constexpr int RSTRIDE = 260;            // 256 floats + 4 pad (16B-aligned rows)
constexpr int BUFSZ   = 64 * RSTRIDE;   // one W-tile: 64 o-rows (66,560 B)

typedef float v2f __attribute__((ext_vector_type(2)));
typedef float v4f __attribute__((ext_vector_type(4)));

// Placement law (R0/R1/R6/R7/R8): effective arch-VGPR pool ~256/SIMD;
// 128-VGPR waves cap at 2/SIMD -> 8 waves/CU max for this footprint, and
// per-heavy-pass time is ~128-131 us at 8 waves/CU regardless of block
// organization (1x8-wave == 2x4-wave, R8). Heavy is plateaued; this round
// attacks the ~67 us tail (reducers + 3 launch gaps) by fusing all four
// stages into one cooperative kernel (grid 256 = 1 block/CU, guaranteed
// co-resident; 3 grid.sync()s replace 3 kernel boundaries).

// fp32 row loader ------------------------------------------------------------
__device__ __forceinline__ void loadrow16f(const float* __restrict__ base,
                                           size_t elem, float* f){
  const float4* p = (const float4*)(base + elem);
  float4 x0=p[0], x1=p[1], x2=p[2], x3=p[3];
  f[0]=x0.x; f[1]=x0.y; f[2]=x0.z; f[3]=x0.w;
  f[4]=x1.x; f[5]=x1.y; f[6]=x1.z; f[7]=x1.w;
  f[8]=x2.x; f[9]=x2.y; f[10]=x2.z; f[11]=x2.w;
  f[12]=x3.x; f[13]=x3.y; f[14]=x3.z; f[15]=x3.w;
}

// async global->LDS, 16 B per lane; lds dst is wave-uniform base + lane*16
__device__ __forceinline__ void gl_lds16(const float* g, float* l){
  __builtin_amdgcn_global_load_lds(
      (const __attribute__((address_space(1))) unsigned int*)g,
      (__attribute__((address_space(3))) unsigned int*)l,
      16, 0, 0);
}

// ---------------- heavy phase (R0-proven body, device function) -------------
// NW waves; wave w owns batches b0=bg*2NW+2w, b1=b0+1 packed into float2
// lanes. Per i: W[:,i,:,:] (64KB) DMA'd to LDS rows [o][256] stride 260
// (double-buffered); lane=o reads its row via ds_read_b128 (conflict-free);
// V, softmax (wave shuffle over o), moments all in registers/packed.
template<int NW, bool ESTEP>
__device__ __forceinline__ void heavy_phase(
    const float* __restrict__ u, const float* __restrict__ W,
    const float* __restrict__ bias,
    const float* __restrict__ mean0, const float* __restrict__ i2v0,
    const float* __restrict__ c0,
    float* __restrict__ S1p, float* __restrict__ S2p, float* __restrict__ Wsp,
    const int CH, float* buf)
{
  const int CI = NI / CH;
  constexpr int ROWS = 64 / NW;
  const int bid = blockIdx.x;
  const int bg = bid / CH, c = bid % CH;
  const int t = threadIdx.x, lane = t & 63, w = t >> 6;
  const int b0 = bg*(2*NW) + 2*w, b1 = b0 + 1;
  const int i0 = c*CI;

  float bs[16]; loadrow16f(bias, (size_t)lane*ND, bs);
  v2f mr[16], ir[16]; v2f c01 = {0.f, 0.f};
  if (ESTEP){
    const size_t m0 = ((size_t)b0*NO + lane)*ND;
    const size_t m1 = ((size_t)b1*NO + lane)*ND;
    #pragma unroll
    for (int e=0;e<16;++e){
      mr[e] = v2f{mean0[m0+e], mean0[m1+e]};
      ir[e] = v2f{i2v0[m0+e], i2v0[m1+e]};
    }
    c01 = v2f{c0[(size_t)b0*NO + lane], c0[(size_t)b1*NO + lane]};
  }

  v2f S1[16], S2[16]; v2f wsum = {0.f, 0.f};
  #pragma unroll
  for (int e=0;e<16;++e){ S1[e]=v2f{0.f,0.f}; S2[e]=v2f{0.f,0.f}; }

  auto stage = [&](int p, int i){
    const float* gbase = W + (size_t)i*256 + (size_t)lane*4;
    float* lbase = &buf[p*BUFSZ];
    #pragma unroll
    for (int r=0;r<ROWS;++r){
      const int o = w*ROWS + r;
      gl_lds16(gbase + (size_t)o*NI*256, lbase + o*RSTRIDE);
    }
  };

  int p = 0;
  stage(0, i0);

  for (int ii=0; ii<CI; ++ii){
    __syncthreads();                      // drains tile-p loads; buffer reuse
    if (ii+1 < CI) stage(p^1, i0+ii+1);   // async, overlaps compute below

    const int i = i0 + ii;
    v2f u01[16];
    {
      const float4* pa = (const float4*)(u + ((size_t)b0*NI + i)*ND);
      const float4* pb = (const float4*)(u + ((size_t)b1*NI + i)*ND);
      #pragma unroll
      for (int q=0;q<4;++q){
        float4 xa = pa[q], xb = pb[q];
        u01[q*4+0] = v2f{xa.x, xb.x};
        u01[q*4+1] = v2f{xa.y, xb.y};
        u01[q*4+2] = v2f{xa.z, xb.z};
        u01[q*4+3] = v2f{xa.w, xb.w};
      }
    }
    v2f ss = {0.f, 0.f};
    #pragma unroll
    for (int d=0;d<16;++d){ v2f x = u01[d] + EPSF; ss += x*x; }
    const v2f av = {sqrtf(ss.x), sqrtf(ss.y)};

    v2f V[16];
    #pragma unroll
    for (int e=0;e<16;++e){ float b = bs[e] + EPSF; V[e] = v2f{b, b}; }
    const float* row = &buf[p*BUFSZ + lane*RSTRIDE];
    #pragma unroll
    for (int e=0;e<16;++e){
      #pragma unroll
      for (int dq=0; dq<4; ++dq){
        const float4 wv = *(const float4*)(row + e*16 + dq*4);
        const int d = dq*4;
        V[e] += wv.x*u01[d+0];
        V[e] += wv.y*u01[d+1];
        V[e] += wv.z*u01[d+2];
        V[e] += wv.w*u01[d+3];
      }
    }

    v2f wg;
    if (ESTEP){
      v2f la = {0.f, 0.f};
      #pragma unroll
      for (int e=0;e<16;++e){ v2f df = V[e]-mr[e]; la += df*df*ir[e]; }
      v2f ap = c01 * v2f{__expf(-la.x), __expf(-la.y)};
      float q0 = ap.x, q1 = ap.y;
      #pragma unroll
      for (int off=32; off; off>>=1){
        q0 += __shfl_xor(q0, off);
        q1 += __shfl_xor(q1, off);
      }
      wg = v2f{ap.x/(q0 + EPSF)*av.x, ap.y/(q1 + EPSF)*av.y};
    } else {
      wg = av;                      // uniform rr: 1/64 applied in mred
    }
    wsum += wg;
    #pragma unroll
    for (int e=0;e<16;++e){
      v2f tv = wg*V[e]; S1[e]+=tv; S2[e]+=tv*V[e];
    }
    p ^= 1;
  }

  const size_t ba = (((size_t)b0*CH + c)*NO + lane);
  const size_t bb = (((size_t)b1*CH + c)*NO + lane);
  #pragma unroll
  for (int e=0;e<16;++e){
    S1p[ba*ND+e]=S1[e].x; S2p[ba*ND+e]=S2[e].x;
    S1p[bb*ND+e]=S1[e].y; S2p[bb*ND+e]=S2[e].y;
  }
  Wsp[ba] = wsum.x; Wsp[bb] = wsum.y;  // m-pass: sum a_i; e-pass: sum rr*a
}

// ---------------- m-reduce, one wave per (b,o) (R5-proven body) -------------
__device__ __forceinline__ void mred_wave(
    const int lane, const int bo, const int CH,
    const float* __restrict__ beta_a, const float* __restrict__ beta_u,
    const float* __restrict__ S1p, const float* __restrict__ S2p,
    const float* __restrict__ Wsp,
    float* __restrict__ mean0, float* __restrict__ i2v0,
    float* __restrict__ c0)
{
  const int b = bo >> 6, o = bo & 63;
  const int q = lane & 3, cgp = lane >> 2;

  v4f s1 = {0.f,0.f,0.f,0.f}, s2 = {0.f,0.f,0.f,0.f};
  for (int c = cgp; c < CH; c += 16){
    const size_t base = ((((size_t)b*CH)+c)*NO + o)*ND + 4*q;
    s1 += *(const v4f*)(S1p + base);
    s2 += *(const v4f*)(S2p + base);
  }
  #pragma unroll
  for (int off=4; off<64; off<<=1){
    #pragma unroll
    for (int k=0;k<4;++k){
      s1[k] += __shfl_xor(s1[k], off);
      s2[k] += __shfl_xor(s2[k], off);
    }
  }
  float wv = 0.f;
  for (int c = lane; c < CH; c += 64)
    wv += Wsp[(((size_t)b*CH)+c)*NO + o];
  #pragma unroll
  for (int off=1; off<64; off<<=1) wv += __shfl_xor(wv, off);

  const float rrsum = wv * (1.f/64.f);
  const float inv = 1.f/(rrsum + EPSF);
  const float bu = beta_u[o];
  v4f T1 = s1*(1.f/64.f), T2 = s2*(1.f/64.f);
  v4f m   = T1*inv;
  v4f var = (T2 - 2.f*m*T1 + m*m*rrsum)*inv + 1e-4f;
  v4f iv;
  float ctp = 0.f, prp = 1.f;
  #pragma unroll
  for (int k=0;k<4;++k){
    iv[k] = 1.f/(2.f*var[k] + EPSF);
    ctp += bu + __logf(var[k]);
    prp *= var[k];
  }
  ctp += __shfl_xor(ctp, 1); ctp += __shfl_xor(ctp, 2);
  prp *= __shfl_xor(prp, 1); prp *= __shfl_xor(prp, 2);

  const size_t mbase = ((size_t)b*NO + o)*ND;
  if (cgp == 0){
    *(v4f*)(mean0 + mbase + 4*q) = m;
    *(v4f*)(i2v0  + mbase + 4*q) = iv;
  }
  if (lane == 0){
    float cost = ctp * rrsum;
    float x  = 5.0e-4f*(beta_a[o] - cost);   // inv_temp iter0 = 0.01*(1-0.95)
    float aj = 1.f/(1.f + __expf(-x));
    float p1 = sqrtf(6.2831853071795864f*prp + EPSF);
    c0[(size_t)b*NO + o] = aj/(p1 + EPSF);
  }
}

// ---------------- final reduce, one wave per (b,o) (R5-proven body) ---------
__device__ __forceinline__ void final_wave(
    const int lane, const int bo, const int CH,
    const float* __restrict__ beta_a, const float* __restrict__ beta_u,
    const float* __restrict__ S1p, const float* __restrict__ S2p,
    const float* __restrict__ Wsp, float* __restrict__ out)
{
  const int b = bo >> 6, o = bo & 63;
  const int q = lane & 3, cgp = lane >> 2;

  v4f s1 = {0.f,0.f,0.f,0.f}, s2 = {0.f,0.f,0.f,0.f};
  for (int c = cgp; c < CH; c += 16){
    const size_t base = ((((size_t)b*CH)+c)*NO + o)*ND + 4*q;
    s1 += *(const v4f*)(S1p + base);
    s2 += *(const v4f*)(S2p + base);
  }
  #pragma unroll
  for (int off=4; off<64; off<<=1){
    #pragma unroll
    for (int k=0;k<4;++k){
      s1[k] += __shfl_xor(s1[k], off);
      s2[k] += __shfl_xor(s2[k], off);
    }
  }
  float wv = 0.f;
  for (int c = lane; c < CH; c += 64)
    wv += Wsp[(((size_t)b*CH)+c)*NO + o];
  #pragma unroll
  for (int off=1; off<64; off<<=1) wv += __shfl_xor(wv, off);

  const float Wsum = wv;
  const float inv = 1.f/(Wsum + EPSF);
  const float bu = beta_u[o];
  v4f m   = s1*inv;
  v4f var = (s2 - 2.f*m*s1 + m*m*Wsum)*inv + 1e-4f;
  float ctp = 0.f, nrm = 0.f;
  #pragma unroll
  for (int k=0;k<4;++k){
    ctp += bu + __logf(var[k]);
    float me = m[k] + EPSF;
    nrm += me*me;
  }
  ctp += __shfl_xor(ctp, 1); ctp += __shfl_xor(ctp, 2);
  nrm += __shfl_xor(nrm, 1); nrm += __shfl_xor(nrm, 2);

  const float cost = ctp * Wsum;
  const float x  = 9.75e-4f*(beta_a[o] - cost);  // inv_temp iter1 = 0.01*(1-0.95^2)
  const float aj = 1.f/(1.f + __expf(-x));
  const float scale = aj/(sqrtf(nrm) + EPSF);
  if (cgp == 0){
    *(v4f*)(out + (size_t)bo*ND + 4*q) = scale*m;
  }
}

// ---------------- fused cooperative kernel ----------------------------------
// grid 256 x 512 = 1 block/CU (133 KB LDS), all co-resident. Phases:
//  1) m-pass heavy (R0 body)          -> S1p/S2p/Wsp
//  2) mred: wave handles 2 (b,o)      -> mean0/i2v0/c0
//  3) e-pass heavy (R0 body)          -> S1p/S2p/Wsp (overwrites)
//  4) final: wave handles 2 (b,o)     -> out
// __threadfence() (agent scope) + grid.sync() at each boundary for cross-XCD
// visibility. Replaces 3 kernel boundaries + 2x4096-tiny-block dispatches.
__global__ __launch_bounds__(512, 2) void k_fused(
    const float* __restrict__ u, const float* __restrict__ W,
    const float* __restrict__ beta_a, const float* __restrict__ beta_u,
    const float* __restrict__ bias,
    float* __restrict__ S1p, float* __restrict__ S2p, float* __restrict__ Wsp,
    float* __restrict__ mean0, float* __restrict__ i2v0, float* __restrict__ c0,
    float* __restrict__ out, const int CH)
{
  __shared__ float buf[2*BUFSZ];   // 133,120 B
  cg::grid_group grid = cg::this_grid();
  const int t = threadIdx.x, lane = t & 63, w = t >> 6;
  const int wbase = ((int)blockIdx.x*8 + w)*2;   // 2 (b,o) per wave, 4096 total

  heavy_phase<8,false>(u, W, bias, nullptr, nullptr, nullptr,
                       S1p, S2p, Wsp, CH, buf);
  __threadfence();
  grid.sync();

  mred_wave(lane, wbase+0, CH, beta_a, beta_u, S1p, S2p, Wsp, mean0, i2v0, c0);
  mred_wave(lane, wbase+1, CH, beta_a, beta_u, S1p, S2p, Wsp, mean0, i2v0, c0);
  __threadfence();
  grid.sync();

  heavy_phase<8,true>(u, W, bias, mean0, i2v0, c0,
                      S1p, S2p, Wsp, CH, buf);
  __threadfence();
  grid.sync();

  final_wave(lane, wbase+0, CH, beta_a, beta_u, S1p, S2p, Wsp, out);
  final_wave(lane, wbase+1, CH, beta_a, beta_u, S1p, S2p, Wsp, out);
}

// ---------------- standalone fallback kernels -------------------------------
template<int NW, bool ESTEP>
__global__ __launch_bounds__(NW*64, 2) void k_heavy(
    const float* __restrict__ u, const float* __restrict__ W,
    const float* __restrict__ bias,
    const float* __restrict__ mean0, const float* __restrict__ i2v0,
    const float* __restrict__ c0,
    float* __restrict__ S1p, float* __restrict__ S2p, float* __restrict__ Wsp,
    const int CH)
{
  __shared__ float buf[2*BUFSZ];
  heavy_phase<NW,ESTEP>(u, W, bias, mean0, i2v0, c0, S1p, S2p, Wsp, CH, buf);
}

__global__ __launch_bounds__(64) void k_mred(
    const float* __restrict__ beta_a, const float* __restrict__ beta_u,
    const float* __restrict__ S1p, const float* __restrict__ S2p,
    const float* __restrict__ Wsp, const int CH,
    float* __restrict__ mean0, float* __restrict__ i2v0, float* __restrict__ c0)
{
  mred_wave((int)threadIdx.x, (int)blockIdx.x, CH,
            beta_a, beta_u, S1p, S2p, Wsp, mean0, i2v0, c0);
}

__global__ __launch_bounds__(64) void k_final(
    const float* __restrict__ beta_a, const float* __restrict__ beta_u,
    const float* __restrict__ S1p, const float* __restrict__ S2p,
    const float* __restrict__ Wsp, const int CH,
    float* __restrict__ out)
{
  final_wave((int)threadIdx.x, (int)blockIdx.x, CH,
             beta_a, beta_u, S1p, S2p, Wsp, out);
}

// ---------------- host ------------------------------------------------------
extern "C" void kernel_launch(void* const* d_in, const int* in_sizes, int n_in,
                              void* d_out, int out_size, void* d_ws, size_t ws_size,
                              hipStream_t stream)
{
  const float* u      = (const float*)d_in[0];
  const float* W      = (const float*)d_in[1];
  const float* beta_a = (const float*)d_in[2];
  const float* beta_u = (const float*)d_in[3];
  const float* bias   = (const float*)d_in[4];
  float* ws  = (float*)d_ws;
  float* out = (float*)d_out;

  const size_t base_f = 2u*NB*NO*ND + NB*NO;                  // 135,168 floats
  auto need = [&](int ch){
    return (base_f + 2u*(size_t)NB*ch*NO*ND + (size_t)NB*ch*NO)*4;
  };
  const bool big = (ws_size >= need(64));
  const int CH = big ? 64 : 32;

  float* mean0= ws;
  float* i2v0 = mean0 + (size_t)NB*NO*ND;
  float* c0   = i2v0 + (size_t)NB*NO*ND;
  float* S1p  = c0   + (size_t)NB*NO;
  float* S2p  = S1p  + (size_t)NB*CH*NO*ND;
  float* Wsp  = S2p  + (size_t)NB*CH*NO*ND;

  bool done = false;
  if (big){
    // fused cooperative path: grid 256 x 512 (1 block/CU, co-resident)
    const float *ua=u, *Wa=W, *baa=beta_a, *bua=beta_u, *bia=bias;
    float *s1a=S1p, *s2a=S2p, *wsa=Wsp, *m0a=mean0, *iva=i2v0, *c0a=c0,
          *oa=out;
    int cha = CH;
    void* args[] = {(void*)&ua, (void*)&Wa, (void*)&baa, (void*)&bua,
                    (void*)&bia, (void*)&s1a, (void*)&s2a, (void*)&wsa,
                    (void*)&m0a, (void*)&iva, (void*)&c0a, (void*)&oa,
                    (void*)&cha};
    hipError_t err = hipLaunchCooperativeKernel(
        (const void*)k_fused, dim3((NB/16)*CH), dim3(512), args, 0, stream);
    done = (err == hipSuccess);
  }
  if (!done){
    // proven 4-kernel path
    if (big){
      const int GRID = (NB/16)*CH;
      k_heavy<8,false><<<GRID, 512, 0, stream>>>(u, W, bias,
                                                 nullptr, nullptr, nullptr,
                                                 S1p, S2p, Wsp, CH);
      k_mred<<<NB*NO, 64, 0, stream>>>(beta_a, beta_u, S1p, S2p, Wsp, CH,
                                       mean0, i2v0, c0);
      k_heavy<8,true><<<GRID, 512, 0, stream>>>(u, W, bias,
                                                mean0, i2v0, c0,
                                                S1p, S2p, Wsp, CH);
    } else {
      const int GRID = (NB/8)*CH;
      k_heavy<4,false><<<GRID, 256, 0, stream>>>(u, W, bias,
                                                 nullptr, nullptr, nullptr,
                                                 S1p, S2p, Wsp, CH);
      k_mred<<<NB*NO, 64, 0, stream>>>(beta_a, beta_u, S1p, S2p, Wsp, CH,
                                       mean0, i2v0, c0);
      k_heavy<4,true><<<GRID, 256, 0, stream>>>(u, W, bias,
                                                mean0, i2v0, c0,
                                                S1p, S2p, Wsp, CH);
    }
    k_final<<<NB*NO, 64, 0, stream>>>(beta_a, beta_u, S1p, S2p, Wsp, CH, out);
  }
}

// Round 10
// 327.871 us; speedup vs baseline: 2.3436x; 2.3436x over previous
//
#include <hip/hip_runtime.h>

#define EPSF 1e-8f

constexpr int NB = 64;   // batch
constexpr int NO = 64;   // out capsules
constexpr int NI = 1152; // in capsules
constexpr int ND = 16;   // pose dims

constexpr int RSTRIDE = 260;            // 256 floats + 4 pad (16B-aligned rows)
constexpr int BUFSZ   = 64 * RSTRIDE;   // one W-tile: 64 o-rows (66,560 B)

typedef float v2f __attribute__((ext_vector_type(2)));
typedef float v4f __attribute__((ext_vector_type(4)));

// Placement law (R0/R1/R6/R7/R8): effective arch-VGPR pool ~256/SIMD;
// 128-VGPR waves cap at 2/SIMD -> 8 waves/CU for this footprint; per-heavy
// pass ~128-131 us regardless of block organization. Cooperative grid.sync
// costs ~110 us each (R9) -- never fuse. This round: m-pass STORES V
// (302 MB, coalesced, into its idle write pipe); e-pass becomes a pure
// HBM stream (no W staging, no LDS, no barriers).

// fp32 row loader ------------------------------------------------------------
__device__ __forceinline__ void loadrow16f(const float* __restrict__ base,
                                           size_t elem, float* f){
  const float4* p = (const float4*)(base + elem);
  float4 x0=p[0], x1=p[1], x2=p[2], x3=p[3];
  f[0]=x0.x; f[1]=x0.y; f[2]=x0.z; f[3]=x0.w;
  f[4]=x1.x; f[5]=x1.y; f[6]=x1.z; f[7]=x1.w;
  f[8]=x2.x; f[9]=x2.y; f[10]=x2.z; f[11]=x2.w;
  f[12]=x3.x; f[13]=x3.y; f[14]=x3.z; f[15]=x3.w;
}

// async global->LDS, 16 B per lane; lds dst is wave-uniform base + lane*16
__device__ __forceinline__ void gl_lds16(const float* g, float* l){
  __builtin_amdgcn_global_load_lds(
      (const __attribute__((address_space(1))) unsigned int*)g,
      (__attribute__((address_space(3))) unsigned int*)l,
      16, 0, 0);
}

// ---------------- m-pass heavy kernel (R8-proven slim body) ----------------
// NW=4 (256-thr), SINGLE 66,560 B tile. Raw moments (bias factored out,
// restored in k_mred). STORV: additionally write V (raw) to Vws for the
// streaming e-pass -- per e-quad, lane=o stores float4 per batch
// (wave: 64 lanes x 16 B at 64 B stride; 4 quads fill the 4 KB (b,i) chunk).
template<bool STORV>
__global__ __launch_bounds__(256, 2) void k_mpass(
    const float* __restrict__ u, const float* __restrict__ W,
    float* __restrict__ S1p, float* __restrict__ S2p, float* __restrict__ Wsp,
    float* __restrict__ Vws, const int CH)
{
  const int CI = NI / CH;
  const int bid = blockIdx.x;
  const int bg = bid / CH, c = bid % CH;
  const int t = threadIdx.x, lane = t & 63, w = t >> 6;
  const int b0 = bg*8 + 2*w, b1 = b0 + 1;
  const int i0 = c*CI;

  __shared__ float buf[BUFSZ];

  v2f S1[16], S2[16]; v2f wsum = {0.f, 0.f};
  #pragma unroll
  for (int e=0;e<16;++e){ S1[e]=v2f{0.f,0.f}; S2[e]=v2f{0.f,0.f}; }

  const float* row = &buf[lane*RSTRIDE];

  for (int ii=0; ii<CI; ++ii){
    const int i = i0 + ii;
    __syncthreads();               // prior column's buf reads complete
    {
      const float* g = W + (size_t)i*256 + (size_t)(w*16)*NI*256
                         + (size_t)lane*4;
      float* l = buf + (w*16)*RSTRIDE;
      #pragma unroll 1
      for (int r=0;r<16;++r){
        gl_lds16(g, l);
        g += (size_t)NI*256;
        l += RSTRIDE;
      }
    }

    v2f u01[16];
    {
      const float4* pa = (const float4*)(u + ((size_t)b0*NI + i)*ND);
      const float4* pb = (const float4*)(u + ((size_t)b1*NI + i)*ND);
      #pragma unroll
      for (int q=0;q<4;++q){
        float4 xa = pa[q], xb = pb[q];
        u01[q*4+0] = v2f{xa.x, xb.x};
        u01[q*4+1] = v2f{xa.y, xb.y};
        u01[q*4+2] = v2f{xa.z, xb.z};
        u01[q*4+3] = v2f{xa.w, xb.w};
      }
    }
    v2f ss = {0.f, 0.f};
    #pragma unroll
    for (int d=0;d<16;++d){ v2f x = u01[d] + EPSF; ss += x*x; }
    const v2f av = {sqrtf(ss.x), sqrtf(ss.y)};

    __syncthreads();               // stage DMA drained

    #pragma unroll
    for (int qd=0; qd<4; ++qd){
      v2f Vq[4];
      #pragma unroll
      for (int eq=0; eq<4; ++eq){
        const int e = qd*4 + eq;
        v2f Ve = {0.f, 0.f};
        #pragma unroll
        for (int dq=0; dq<4; ++dq){
          const float4 wv = *(const float4*)(row + e*16 + dq*4);
          const int d = dq*4;
          Ve += wv.x*u01[d+0];
          Ve += wv.y*u01[d+1];
          Ve += wv.z*u01[d+2];
          Ve += wv.w*u01[d+3];
        }
        v2f tv = av*Ve;
        S1[e] += tv;
        S2[e] += tv*Ve;
        Vq[eq] = Ve;
      }
      if (STORV){
        float4 va = {Vq[0].x, Vq[1].x, Vq[2].x, Vq[3].x};
        float4 vb = {Vq[0].y, Vq[1].y, Vq[2].y, Vq[3].y};
        *(float4*)(Vws + (((size_t)b0*NI + i)*NO + lane)*ND + 4*qd) = va;
        *(float4*)(Vws + (((size_t)b1*NI + i)*NO + lane)*ND + 4*qd) = vb;
      }
    }
    wsum += av;
  }

  const size_t ba = (((size_t)b0*CH + c)*NO + lane);
  const size_t bb = (((size_t)b1*CH + c)*NO + lane);
  #pragma unroll
  for (int e=0;e<16;++e){
    S1p[ba*ND+e]=S1[e].x; S2p[ba*ND+e]=S2[e].x;
    S1p[bb*ND+e]=S1[e].y; S2p[bb*ND+e]=S2[e].y;
  }
  Wsp[ba] = wsum.x; Wsp[bb] = wsum.y;   // = per-slice sum of a_i
}

// ---------------- e-pass: pure V stream (no LDS, no barriers) ---------------
// 4 waves/block, 1 batch/wave, lane=o. Per column: read V[b,i,:,:] (wave reads
// 4 KB contiguous), recompute av from u (broadcast row, L2-hot), softmax over
// o via wave shuffle, accumulate RAW moments (bias restored in k_final<RAW>).
// mrB = mean0 - (bias+EPS) so la uses raw V exactly: Vraw - mrB = Vfull - mr.
__global__ __launch_bounds__(256, 2) void k_epass(
    const float* __restrict__ u, const float* __restrict__ Vws,
    const float* __restrict__ mean0, const float* __restrict__ i2v0,
    const float* __restrict__ c0, const float* __restrict__ bias,
    float* __restrict__ S1p, float* __restrict__ S2p, float* __restrict__ Wsp,
    const int CH)
{
  const int CI = NI / CH;
  const int bid = blockIdx.x;
  const int bg = bid / CH, c = bid % CH;
  const int t = threadIdx.x, lane = t & 63, w = t >> 6;
  const int b = bg*4 + w;
  const int i0 = c*CI;

  float mrB[16], ir[16];
  {
    const size_t m0 = ((size_t)b*NO + lane)*ND;
    #pragma unroll
    for (int q=0;q<4;++q){
      float4 mm = *(const float4*)(mean0 + m0 + 4*q);
      float4 iv = *(const float4*)(i2v0 + m0 + 4*q);
      float4 bq = *(const float4*)(bias + (size_t)lane*ND + 4*q);
      mrB[4*q+0]=mm.x-(bq.x+EPSF); mrB[4*q+1]=mm.y-(bq.y+EPSF);
      mrB[4*q+2]=mm.z-(bq.z+EPSF); mrB[4*q+3]=mm.w-(bq.w+EPSF);
      ir[4*q+0]=iv.x; ir[4*q+1]=iv.y; ir[4*q+2]=iv.z; ir[4*q+3]=iv.w;
    }
  }
  const float cc = c0[(size_t)b*NO + lane];

  float S1[16], S2[16]; float wsum = 0.f;
  #pragma unroll
  for (int e=0;e<16;++e){ S1[e]=0.f; S2[e]=0.f; }

  for (int ii=0; ii<CI; ++ii){
    const int i = i0 + ii;
    float V[16];
    {
      const float4* pv =
        (const float4*)(Vws + (((size_t)b*NI + i)*NO + lane)*ND);
      #pragma unroll
      for (int q=0;q<4;++q){
        float4 x = pv[q];
        V[4*q+0]=x.x; V[4*q+1]=x.y; V[4*q+2]=x.z; V[4*q+3]=x.w;
      }
    }
    // av = ||u+EPS|| recomputed (same op order as m-pass)
    float uu[16];
    loadrow16f(u, ((size_t)b*NI + i)*ND, uu);
    float ss = 0.f;
    #pragma unroll
    for (int d=0;d<16;++d){ float x = uu[d] + EPSF; ss += x*x; }
    const float av = sqrtf(ss);

    float la = 0.f;
    #pragma unroll
    for (int e=0;e<16;++e){ float df = V[e]-mrB[e]; la += df*df*ir[e]; }
    float ap = cc*__expf(-la);
    float qs = ap;
    #pragma unroll
    for (int off=32; off; off>>=1) qs += __shfl_xor(qs, off);
    const float wg = ap/(qs + EPSF)*av;
    wsum += wg;
    #pragma unroll
    for (int e=0;e<16;++e){ float tv = wg*V[e]; S1[e]+=tv; S2[e]+=tv*V[e]; }
  }

  const size_t ba = (((size_t)b*CH + c)*NO + lane);
  #pragma unroll
  for (int e=0;e<16;++e){ S1p[ba*ND+e]=S1[e]; S2p[ba*ND+e]=S2[e]; }
  Wsp[ba] = wsum;
}

// ---------------- e-pass fallback (R0-proven heavy, bias-inclusive) ---------
template<int NW>
__global__ __launch_bounds__(NW*64, 2) void k_heavy_e(
    const float* __restrict__ u, const float* __restrict__ W,
    const float* __restrict__ bias,
    const float* __restrict__ mean0, const float* __restrict__ i2v0,
    const float* __restrict__ c0,
    float* __restrict__ S1p, float* __restrict__ S2p, float* __restrict__ Wsp,
    const int CH)
{
  const int CI = NI / CH;
  constexpr int ROWS = 64 / NW;
  const int bid = blockIdx.x;
  const int bg = bid / CH, c = bid % CH;
  const int t = threadIdx.x, lane = t & 63, w = t >> 6;
  const int b0 = bg*(2*NW) + 2*w, b1 = b0 + 1;
  const int i0 = c*CI;

  __shared__ float buf[2*BUFSZ];

  float bs[16]; loadrow16f(bias, (size_t)lane*ND, bs);
  v2f mr[16], ir[16]; v2f c01;
  {
    const size_t m0 = ((size_t)b0*NO + lane)*ND;
    const size_t m1 = ((size_t)b1*NO + lane)*ND;
    #pragma unroll
    for (int e=0;e<16;++e){
      mr[e] = v2f{mean0[m0+e], mean0[m1+e]};
      ir[e] = v2f{i2v0[m0+e], i2v0[m1+e]};
    }
    c01 = v2f{c0[(size_t)b0*NO + lane], c0[(size_t)b1*NO + lane]};
  }

  v2f S1[16], S2[16]; v2f wsum = {0.f, 0.f};
  #pragma unroll
  for (int e=0;e<16;++e){ S1[e]=v2f{0.f,0.f}; S2[e]=v2f{0.f,0.f}; }

  auto stage = [&](int p, int i){
    const float* gbase = W + (size_t)i*256 + (size_t)lane*4;
    float* lbase = &buf[p*BUFSZ];
    #pragma unroll
    for (int r=0;r<ROWS;++r){
      const int o = w*ROWS + r;
      gl_lds16(gbase + (size_t)o*NI*256, lbase + o*RSTRIDE);
    }
  };

  int p = 0;
  stage(0, i0);

  for (int ii=0; ii<CI; ++ii){
    __syncthreads();
    if (ii+1 < CI) stage(p^1, i0+ii+1);

    const int i = i0 + ii;
    v2f u01[16];
    {
      const float4* pa = (const float4*)(u + ((size_t)b0*NI + i)*ND);
      const float4* pb = (const float4*)(u + ((size_t)b1*NI + i)*ND);
      #pragma unroll
      for (int q=0;q<4;++q){
        float4 xa = pa[q], xb = pb[q];
        u01[q*4+0] = v2f{xa.x, xb.x};
        u01[q*4+1] = v2f{xa.y, xb.y};
        u01[q*4+2] = v2f{xa.z, xb.z};
        u01[q*4+3] = v2f{xa.w, xb.w};
      }
    }
    v2f ss = {0.f, 0.f};
    #pragma unroll
    for (int d=0;d<16;++d){ v2f x = u01[d] + EPSF; ss += x*x; }
    const v2f av = {sqrtf(ss.x), sqrtf(ss.y)};

    v2f V[16];
    #pragma unroll
    for (int e=0;e<16;++e){ float b = bs[e] + EPSF; V[e] = v2f{b, b}; }
    const float* row = &buf[p*BUFSZ + lane*RSTRIDE];
    #pragma unroll
    for (int e=0;e<16;++e){
      #pragma unroll
      for (int dq=0; dq<4; ++dq){
        const float4 wv = *(const float4*)(row + e*16 + dq*4);
        const int d = dq*4;
        V[e] += wv.x*u01[d+0];
        V[e] += wv.y*u01[d+1];
        V[e] += wv.z*u01[d+2];
        V[e] += wv.w*u01[d+3];
      }
    }

    v2f la = {0.f, 0.f};
    #pragma unroll
    for (int e=0;e<16;++e){ v2f df = V[e]-mr[e]; la += df*df*ir[e]; }
    v2f ap = c01 * v2f{__expf(-la.x), __expf(-la.y)};
    float q0 = ap.x, q1 = ap.y;
    #pragma unroll
    for (int off=32; off; off>>=1){
      q0 += __shfl_xor(q0, off);
      q1 += __shfl_xor(q1, off);
    }
    v2f wg = v2f{ap.x/(q0 + EPSF)*av.x, ap.y/(q1 + EPSF)*av.y};
    wsum += wg;
    #pragma unroll
    for (int e=0;e<16;++e){
      v2f tv = wg*V[e]; S1[e]+=tv; S2[e]+=tv*V[e];
    }
    p ^= 1;
  }

  const size_t ba = (((size_t)b0*CH + c)*NO + lane);
  const size_t bb = (((size_t)b1*CH + c)*NO + lane);
  #pragma unroll
  for (int e=0;e<16;++e){
    S1p[ba*ND+e]=S1[e].x; S2p[ba*ND+e]=S2[e].x;
    S1p[bb*ND+e]=S1[e].y; S2p[bb*ND+e]=S2[e].y;
  }
  Wsp[ba] = wsum.x; Wsp[bb] = wsum.y;
}

// ---------------- reduce m-step partials -> mean0,i2v0,c0 -------------------
// Wave-parallel (R5) + exact bias restoration for raw m-pass partials.
__global__ __launch_bounds__(64) void k_mred(
    const float* __restrict__ beta_a, const float* __restrict__ beta_u,
    const float* __restrict__ bias,
    const float* __restrict__ S1p, const float* __restrict__ S2p,
    const float* __restrict__ Wsp, const int CH,
    float* __restrict__ mean0, float* __restrict__ i2v0, float* __restrict__ c0)
{
  const int bo = blockIdx.x;
  const int b = bo >> 6, o = bo & 63;
  const int t = threadIdx.x;
  const int q = t & 3, cg = t >> 2;

  v4f s1 = {0.f,0.f,0.f,0.f}, s2 = {0.f,0.f,0.f,0.f};
  for (int c = cg; c < CH; c += 16){
    const size_t base = ((((size_t)b*CH)+c)*NO + o)*ND + 4*q;
    s1 += *(const v4f*)(S1p + base);
    s2 += *(const v4f*)(S2p + base);
  }
  #pragma unroll
  for (int off=4; off<64; off<<=1){
    #pragma unroll
    for (int k=0;k<4;++k){
      s1[k] += __shfl_xor(s1[k], off);
      s2[k] += __shfl_xor(s2[k], off);
    }
  }
  float wv = 0.f;
  for (int c = t; c < CH; c += 64)
    wv += Wsp[(((size_t)b*CH)+c)*NO + o];
  #pragma unroll
  for (int off=1; off<64; off<<=1) wv += __shfl_xor(wv, off);

  {
    v4f Bq = *(const v4f*)(bias + (size_t)o*ND + 4*q);
    Bq += EPSF;
    s2 += 2.f*Bq*s1 + Bq*Bq*wv;
    s1 += Bq*wv;
  }

  const float rrsum = wv * (1.f/64.f);
  const float inv = 1.f/(rrsum + EPSF);
  const float bu = beta_u[o];
  v4f T1 = s1*(1.f/64.f), T2 = s2*(1.f/64.f);
  v4f m   = T1*inv;
  v4f var = (T2 - 2.f*m*T1 + m*m*rrsum)*inv + 1e-4f;
  v4f iv;
  float ctp = 0.f, prp = 1.f;
  #pragma unroll
  for (int k=0;k<4;++k){
    iv[k] = 1.f/(2.f*var[k] + EPSF);
    ctp += bu + __logf(var[k]);
    prp *= var[k];
  }
  ctp += __shfl_xor(ctp, 1); ctp += __shfl_xor(ctp, 2);
  prp *= __shfl_xor(prp, 1); prp *= __shfl_xor(prp, 2);

  const size_t mbase = ((size_t)b*NO + o)*ND;
  if (cg == 0){
    *(v4f*)(mean0 + mbase + 4*q) = m;
    *(v4f*)(i2v0  + mbase + 4*q) = iv;
  }
  if (t == 0){
    float cost = ctp * rrsum;
    float x  = 5.0e-4f*(beta_a[o] - cost);   // inv_temp iter0 = 0.01*(1-0.95)
    float aj = 1.f/(1.f + __expf(-x));
    float p1 = sqrtf(6.2831853071795864f*prp + EPSF);
    c0[(size_t)b*NO + o] = aj/(p1 + EPSF);
  }
}

// ---------------- final reduce; RAW => restore bias into moments ------------
template<bool RAW>
__global__ __launch_bounds__(64) void k_final(
    const float* __restrict__ beta_a, const float* __restrict__ beta_u,
    const float* __restrict__ bias,
    const float* __restrict__ S1p, const float* __restrict__ S2p,
    const float* __restrict__ Wsp, const int CH,
    float* __restrict__ out)
{
  const int bo = blockIdx.x;
  const int b = bo >> 6, o = bo & 63;
  const int t = threadIdx.x;
  const int q = t & 3, cg = t >> 2;

  v4f s1 = {0.f,0.f,0.f,0.f}, s2 = {0.f,0.f,0.f,0.f};
  for (int c = cg; c < CH; c += 16){
    const size_t base = ((((size_t)b*CH)+c)*NO + o)*ND + 4*q;
    s1 += *(const v4f*)(S1p + base);
    s2 += *(const v4f*)(S2p + base);
  }
  #pragma unroll
  for (int off=4; off<64; off<<=1){
    #pragma unroll
    for (int k=0;k<4;++k){
      s1[k] += __shfl_xor(s1[k], off);
      s2[k] += __shfl_xor(s2[k], off);
    }
  }
  float wv = 0.f;
  for (int c = t; c < CH; c += 64)
    wv += Wsp[(((size_t)b*CH)+c)*NO + o];
  #pragma unroll
  for (int off=1; off<64; off<<=1) wv += __shfl_xor(wv, off);

  if (RAW){
    v4f Bq = *(const v4f*)(bias + (size_t)o*ND + 4*q);
    Bq += EPSF;
    s2 += 2.f*Bq*s1 + Bq*Bq*wv;
    s1 += Bq*wv;
  }

  const float Wsum = wv;
  const float inv = 1.f/(Wsum + EPSF);
  const float bu = beta_u[o];
  v4f m   = s1*inv;
  v4f var = (s2 - 2.f*m*s1 + m*m*Wsum)*inv + 1e-4f;
  float ctp = 0.f, nrm = 0.f;
  #pragma unroll
  for (int k=0;k<4;++k){
    ctp += bu + __logf(var[k]);
    float me = m[k] + EPSF;
    nrm += me*me;
  }
  ctp += __shfl_xor(ctp, 1); ctp += __shfl_xor(ctp, 2);
  nrm += __shfl_xor(nrm, 1); nrm += __shfl_xor(nrm, 2);

  const float cost = ctp * Wsum;
  const float x  = 9.75e-4f*(beta_a[o] - cost);  // inv_temp iter1 = 0.01*(1-0.95^2)
  const float aj = 1.f/(1.f + __expf(-x));
  const float scale = aj/(sqrtf(nrm) + EPSF);
  if (cg == 0){
    *(v4f*)(out + (size_t)bo*ND + 4*q) = scale*m;
  }
}

// ---------------- host ------------------------------------------------------
extern "C" void kernel_launch(void* const* d_in, const int* in_sizes, int n_in,
                              void* d_out, int out_size, void* d_ws, size_t ws_size,
                              hipStream_t stream)
{
  const float* u      = (const float*)d_in[0];
  const float* W      = (const float*)d_in[1];
  const float* beta_a = (const float*)d_in[2];
  const float* beta_u = (const float*)d_in[3];
  const float* bias   = (const float*)d_in[4];
  float* ws  = (float*)d_ws;
  float* out = (float*)d_out;

  const size_t base_f = 2u*NB*NO*ND + NB*NO;                  // 135,168 floats
  auto need = [&](int ch){
    return (base_f + 2u*(size_t)NB*ch*NO*ND + (size_t)NB*ch*NO)*4;
  };
  const size_t vws_f = (size_t)NB*NI*NO*ND;                   // 75,497,472
  const size_t need_v = need(64) + vws_f*4;                   // ~337 MB

  const bool vpath = (ws_size >= need_v);
  const bool big   = (ws_size >= need(64));
  const int CH = big ? 64 : 32;

  float* mean0= ws;
  float* i2v0 = mean0 + (size_t)NB*NO*ND;
  float* c0   = i2v0 + (size_t)NB*NO*ND;
  float* S1p  = c0   + (size_t)NB*NO;
  float* S2p  = S1p  + (size_t)NB*CH*NO*ND;
  float* Wsp  = S2p  + (size_t)NB*CH*NO*ND;
  float* Vws  = Wsp  + (size_t)NB*CH*NO;

  // m-pass (raw moments) + m-reduce with bias restoration
  if (vpath){
    k_mpass<true><<<(NB/8)*CH, 256, 0, stream>>>(u, W, S1p, S2p, Wsp,
                                                 Vws, CH);
  } else {
    k_mpass<false><<<(NB/8)*CH, 256, 0, stream>>>(u, W, S1p, S2p, Wsp,
                                                  Vws, CH);
  }
  k_mred<<<NB*NO, 64, 0, stream>>>(beta_a, beta_u, bias, S1p, S2p, Wsp, CH,
                                   mean0, i2v0, c0);

  if (vpath){
    // streaming e-pass (raw moments) + final with bias restoration
    k_epass<<<(NB/4)*CH, 256, 0, stream>>>(u, Vws, mean0, i2v0, c0, bias,
                                           S1p, S2p, Wsp, CH);
    k_final<true><<<NB*NO, 64, 0, stream>>>(beta_a, beta_u, bias,
                                            S1p, S2p, Wsp, CH, out);
  } else if (big){
    k_heavy_e<8><<<(NB/16)*CH, 512, 0, stream>>>(u, W, bias,
                                                 mean0, i2v0, c0,
                                                 S1p, S2p, Wsp, CH);
    k_final<false><<<NB*NO, 64, 0, stream>>>(beta_a, beta_u, bias,
                                             S1p, S2p, Wsp, CH, out);
  } else {
    k_heavy_e<4><<<(NB/8)*CH, 256, 0, stream>>>(u, W, bias,
                                                mean0, i2v0, c0,
                                                S1p, S2p, Wsp, CH);
    k_final<false><<<NB*NO, 64, 0, stream>>>(beta_a, beta_u, bias,
                                             S1p, S2p, Wsp, CH, out);
  }
}